// Round 6
// baseline (349.254 us; speedup 1.0000x reference)
//
#include <hip/hip_runtime.h>
#include <hip/hip_fp16.h>
#include <math.h>

#define N_ATOMS 512
#define F_DIM   128
#define K_RBF   301
#define NLAYER  3
#define GAMMA_C 10.0f
#define LOG2_C  0.6931471805599453f

// Filter lookup table: w_l(d) sampled at step TAB_H; max d = 10*sqrt(3) = 17.32
#define TAB_H     0.01f
#define TAB_INVH  100.0f
#define TAB_ROWS  1768          // 221 * 8, covers up to 17.67
#define RPB       8             // table rows emitted per task (computes RPB+1)
#define NGROUPS   (TAB_ROWS / RPB)          // 221
#define NTASKS    (NGROUPS * NLAYER)        // 663 (row-group, layer) tasks
#define NBBLK2    ((NTASKS + 1) / 2)        // 332 build blocks, 2 tasks each
#define ROW_BYTES 512           // 64 f-pairs * 8 B (uint2 per pair)

#define JSPLIT  8               // conv j-dimension split
#define JPB     (N_ATOMS / JSPLIT)   // 64 j per conv block

__device__ __forceinline__ float ssp(float x) {
    float ax = fabsf(x);
    return fmaxf(x, 0.0f) + log1pf(expf(-ax)) - LOG2_C;
}
__device__ __forceinline__ __half2 u2h2(unsigned u) {
    union { unsigned u; __half2 h; } c; c.u = u; return c.h;
}
__device__ __forceinline__ unsigned h22u(__half2 h) {
    union { unsigned u; __half2 h; } c; c.h = h; return c.u;
}

// Point-to-point cross-XCD coherent accesses, compiler-generated (no asm
// operands to get wrong).  RELAXED + AGENT scope emits sc-flagged
// global_load/store with NO fence instructions — no L2 writeback/invalidate
// (round-3 lesson: ACQ_REL fencing = per-block L2 flush storm, 4x slowdown;
// round-5 lesson: hand-written multi-operand asm = register-allocation bug).
__device__ __forceinline__ void cstore(float* p, float v) {
    __hip_atomic_store(p, v, __ATOMIC_RELAXED, __HIP_MEMORY_SCOPE_AGENT);
}
__device__ __forceinline__ float cload(const float* p) {
    return __hip_atomic_load(p, __ATOMIC_RELAXED, __HIP_MEMORY_SCOPE_AGENT);
}

// ---------------------------------------------------------------------------
// Fused prep + table build.  grid: (512 + 332) x 256
// Atom blocks: distances + embedding + layer-0 atomwise (2-way g-split GEMV).
// Build blocks: filter table.  Block N_ATOMS also zeroes the tail counters.
__global__ void __launch_bounds__(256)
prep_build(const int* __restrict__ x, const float* __restrict__ r,
           const float* __restrict__ emb,
           const float* __restrict__ aw_W, const float* __restrict__ aw_b,
           const float* __restrict__ cf_W1, const float* __restrict__ cf_b1,
           const float* __restrict__ cf_W2, const float* __restrict__ cf_b2,
           uint2* __restrict__ dpk, float* __restrict__ h,
           unsigned* __restrict__ opk, uint2* __restrict__ ptab,
           unsigned* __restrict__ cnt) {
    __shared__ float hs[F_DIM];
    __shared__ float os[F_DIM];
    __shared__ float red2[2 * F_DIM];
    __shared__ float e_s[2][RPB + 1][34];
    __shared__ float w1_s[2][F_DIM][12];

    if (blockIdx.x < N_ATOMS) {
        // ---- prep path: distances + embedding + layer-0 atomwise ----
        int i = blockIdx.x;
        int t = threadIdx.x;
        float rx = r[i * 3 + 0], ry = r[i * 3 + 1], rz = r[i * 3 + 2];
        if (t < F_DIM) {
            float hv = emb[x[i] * F_DIM + t];
            h[i * F_DIM + t] = hv;
            hs[t] = hv;
        }
        for (int j = t; j < N_ATOMS; j += 256) {
            float dx = rx - r[j * 3 + 0];
            float dy = ry - r[j * 3 + 1];
            float dz = rz - r[j * 3 + 2];
            float d  = sqrtf(dx * dx + dy * dy + dz * dz);
            float xb = d * TAB_INVH;
            int   b  = ::min((int)xb, TAB_ROWS - 2);
            float fr = xb - (float)b;
            __half fh = __float2half(fr);
            dpk[i * N_ATOMS + j] = make_uint2((unsigned)b * ROW_BYTES,
                                              h22u(__halves2half2(fh, fh)));
        }
        __syncthreads();
        // 2-way g-split atomwise GEMV across all 256 threads
        {
            int q = t >> 7, f = t & 127;
            float a = 0.0f;
            int g0 = q * 64;
            for (int g = 0; g < 64; ++g)
                a = fmaf(hs[g0 + g], aw_W[(g0 + g) * F_DIM + f], a);
            red2[q * F_DIM + f] = a;
        }
        __syncthreads();
        if (t < F_DIM) os[t] = red2[t] + red2[F_DIM + t] + aw_b[t];
        __syncthreads();
        if (t < F_DIM / 2)
            opk[i * 64 + t] = h22u(__halves2half2(__float2half(os[2 * t]),
                                                  __float2half(os[2 * t + 1])));
        return;
    }

    // zero the per-atom tail counters (consumed by the conv_node dispatches;
    // dispatch boundary publishes them coherently)
    if (blockIdx.x == N_ATOMS) {
        for (int k = threadIdx.x; k < NLAYER * N_ATOMS; k += 256) cnt[k] = 0u;
    }

    // ---- build path: 2 (row-group, layer) tasks per block ----
    int u = threadIdx.x >> 7;
    int f = threadIdx.x & 127;
    int task = (blockIdx.x - N_ATOMS) * 2 + u;
    bool valid = task < NTASKS;
    task = valid ? task : NTASKS - 1;
    int l    = task / NGROUPS;
    int row0 = (task % NGROUPS) * RPB;

    float dlo = row0 * TAB_H;
    float dhi = (row0 + RPB) * TAB_H;
    // Gaussian window: exp(-10*1.45^2) ~ 7.6e-10 truncation
    int k0 = ::max(0, (int)ceilf((dlo - 1.45f) * 10.0f));
    int k1 = ::min(K_RBF - 1, (int)floorf((dhi + 1.45f) * 10.0f));
    int kw = k1 - k0 + 1;

    for (int idx = f; idx < (RPB + 1) * kw; idx += F_DIM) {
        int rr = idx / kw, kk = idx % kw;
        float dv = (row0 + rr) * TAB_H;
        float tt = dv - 0.1f * (float)(k0 + kk);
        e_s[u][rr][kk] = expf(-GAMMA_C * tt * tt);
    }
    __syncthreads();

    const float* W1 = cf_W1 + l * K_RBF * F_DIM;
    float b1v = cf_b1[l * F_DIM + f];
    float acc[RPB + 1];
#pragma unroll
    for (int rr = 0; rr <= RPB; ++rr) acc[rr] = b1v;
    for (int kk = 0; kk < kw; ++kk) {
        float w1v = W1[(k0 + kk) * F_DIM + f];
#pragma unroll
        for (int rr = 0; rr <= RPB; ++rr) acc[rr] = fmaf(e_s[u][rr][kk], w1v, acc[rr]);
    }
#pragma unroll
    for (int rr = 0; rr <= RPB; ++rr) w1_s[u][f][rr] = ssp(acc[rr]);
    __syncthreads();

    const float* W2 = cf_W2 + l * F_DIM * F_DIM;
    float b2v = cf_b2[l * F_DIM + f];
    float acc2[RPB + 1];
#pragma unroll
    for (int rr = 0; rr <= RPB; ++rr) acc2[rr] = b2v;
    for (int g = 0; g < F_DIM; ++g) {
        float w2v = W2[g * F_DIM + f];
        float4 wa = *(const float4*)&w1_s[u][g][0];
        float4 wb = *(const float4*)&w1_s[u][g][4];
        float  wc = w1_s[u][g][8];
        acc2[0] = fmaf(wa.x, w2v, acc2[0]);
        acc2[1] = fmaf(wa.y, w2v, acc2[1]);
        acc2[2] = fmaf(wa.z, w2v, acc2[2]);
        acc2[3] = fmaf(wa.w, w2v, acc2[3]);
        acc2[4] = fmaf(wb.x, w2v, acc2[4]);
        acc2[5] = fmaf(wb.y, w2v, acc2[5]);
        acc2[6] = fmaf(wb.z, w2v, acc2[6]);
        acc2[7] = fmaf(wb.w, w2v, acc2[7]);
        acc2[8] = fmaf(wc,   w2v, acc2[8]);
    }
    float o9[RPB + 1];
#pragma unroll
    for (int rr = 0; rr <= RPB; ++rr) o9[rr] = ssp(acc2[rr]);

    // pack via same-wave shfl with lane f^1; even lanes write pair p=f>>1
    if (valid) {
        int p = f >> 1;
        bool odd = (f & 1);
#pragma unroll
        for (int rr = 0; rr < RPB; ++rr) {
            float t0 = o9[rr];
            float dt = o9[rr + 1] - o9[rr];
            float ot0 = __shfl_xor(t0, 1, 64);
            float odt = __shfl_xor(dt, 1, 64);
            if (!odd) {
                uint2 v = make_uint2(
                    h22u(__halves2half2(__float2half(t0), __float2half(ot0))),
                    h22u(__halves2half2(__float2half(dt), __float2half(odt))));
                ptab[((size_t)l * TAB_ROWS + row0 + rr) * 64 + p] = v;
            }
        }
    }
}

// ---------------------------------------------------------------------------
// Conv (8-way j-split) with fence-free last-finisher node tail.
// grid: (512*8) x 256, 8 blocks/CU.  Block (i, qs) accumulates c-partials
// over 64 j, publishes them with relaxed agent-scope stores (sc-flagged, no
// cache maintenance), waits vmcnt(0), bumps a RELAXED per-atom counter.
// The 8th finisher reads the partials with relaxed agent-scope loads and
// runs the node MLP inline.  No spinning, no fences.
__global__ void __launch_bounds__(256, 8)
conv_node(const uint2* __restrict__ dpk, const unsigned* __restrict__ opk_in,
          const uint2* __restrict__ ptab, float* __restrict__ c_part,
          unsigned* __restrict__ cnt,
          const float* __restrict__ n_W1, const float* __restrict__ n_b1,
          const float* __restrict__ n_W2, const float* __restrict__ n_b2,
          float* __restrict__ h,
          const float* __restrict__ aw_W, const float* __restrict__ aw_b,
          unsigned* __restrict__ opk_out,
          const float* __restrict__ oW1, const float* __restrict__ ob1,
          const float* __restrict__ oW2, const float* __restrict__ ob2,
          float* __restrict__ out, int l) {
    int bid = blockIdx.x;
    int i  = bid >> 3;
    int qs = bid & 7;
    int t  = threadIdx.x;
    int p2 = t & 31;
    int jc = t >> 5;            // 0..7

    __shared__ __align__(16) uint2 ds[JPB];              // 512 B
    __shared__ __align__(16) float redbuf[8 * 32 * 4];   // 4 KB, multi-use
    __shared__ __align__(16) float cs[F_DIM];
    __shared__ __align__(16) float t1s[F_DIM];
    __shared__ __align__(16) float hs[F_DIM];
    __shared__ int lastflag;

    if (t < JPB) ds[t] = dpk[i * N_ATOMS + qs * JPB + t];
    __syncthreads();

    const char*  T  = (const char*)(ptab + (size_t)l * TAB_ROWS * 64) + p2 * 16;
    const uint2* ob = (const uint2*)opk_in + p2 + (size_t)(qs * JPB) * 32;

    int j0 = jc * 8;
    uint2 e[8];
#pragma unroll
    for (int k2 = 0; k2 < 4; ++k2) {
        uint4 w = *(const uint4*)&ds[j0 + 2 * k2];
        e[2 * k2]     = make_uint2(w.x, w.y);
        e[2 * k2 + 1] = make_uint2(w.z, w.w);
    }

    float4 acc = make_float4(0.0f, 0.0f, 0.0f, 0.0f);
#pragma unroll
    for (int b = 0; b < 2; ++b) {
        uint4 tv[4]; uint2 oh[4];
#pragma unroll
        for (int k = 0; k < 4; ++k) {
            tv[k] = *(const uint4*)(T + e[b * 4 + k].x);
            oh[k] = ob[(j0 + b * 4 + k) * 32];
        }
#pragma unroll
        for (int k = 0; k < 4; ++k) {
            __half2 fr2 = u2h2(e[b * 4 + k].y);
            __half2 wa = __hfma2(fr2, u2h2(tv[k].y), u2h2(tv[k].x));
            __half2 wb = __hfma2(fr2, u2h2(tv[k].w), u2h2(tv[k].z));
            __half2 oa  = u2h2(oh[k].x);
            __half2 obh = u2h2(oh[k].y);
            acc.x = fmaf(__half2float(__low2half(wa)),  __half2float(__low2half(oa)),  acc.x);
            acc.y = fmaf(__half2float(__high2half(wa)), __half2float(__high2half(oa)), acc.y);
            acc.z = fmaf(__half2float(__low2half(wb)),  __half2float(__low2half(obh)), acc.z);
            acc.w = fmaf(__half2float(__high2half(wb)), __half2float(__high2half(obh)), acc.w);
        }
    }
    *(float4*)&redbuf[(jc * 32 + p2) * 4] = acc;
    __syncthreads();
    if (t < 32) {
        float4 s = *(const float4*)&redbuf[t * 4];
#pragma unroll
        for (int g = 1; g < 8; ++g) {
            float4 v = *(const float4*)&redbuf[(g * 32 + t) * 4];
            s.x += v.x; s.y += v.y; s.z += v.z; s.w += v.w;
        }
        // coherent publication (relaxed agent-scope stores, no fences)
        float* cp = &c_part[((size_t)(i * JSPLIT + qs)) * F_DIM + 4 * t];
        cstore(cp + 0, s.x);
        cstore(cp + 1, s.y);
        cstore(cp + 2, s.z);
        cstore(cp + 3, s.w);
    }
    // wave 0 (contains lanes 0-31 and t==0): partial stores reach the
    // coherence point before the counter bump is issued.
    asm volatile("s_waitcnt vmcnt(0)" ::: "memory");
    if (t == 0) {
        unsigned old = __hip_atomic_fetch_add(&cnt[i], 1u, __ATOMIC_RELAXED,
                                              __HIP_MEMORY_SCOPE_AGENT);
        lastflag = (old == JSPLIT - 1);
    }
    __syncthreads();
    if (!lastflag) return;

    // ---- node tail for atom i (runs in exactly one block) ----
    if (t < F_DIM) {
        const float* cp = c_part + (size_t)i * JSPLIT * F_DIM + t;
        float o0 = cload(cp + 0 * F_DIM);
        float o1 = cload(cp + 1 * F_DIM);
        float o2 = cload(cp + 2 * F_DIM);
        float o3 = cload(cp + 3 * F_DIM);
        float o4 = cload(cp + 4 * F_DIM);
        float o5 = cload(cp + 5 * F_DIM);
        float o6 = cload(cp + 6 * F_DIM);
        float o7 = cload(cp + 7 * F_DIM);
        cs[t] = ((o0 + o1) + (o2 + o3)) + ((o4 + o5) + (o6 + o7));
        hs[t] = h[i * F_DIM + t];
    }
    __syncthreads();

    // phase A: t1s = ssp(cs @ W1 + b1), 2-way g-split
    {
        int q = t >> 7, f = t & 127;
        const float* W1 = n_W1 + l * F_DIM * F_DIM;
        float a = 0.0f;
        int g0 = q * 64;
        for (int g = 0; g < 64; ++g) a = fmaf(cs[g0 + g], W1[(g0 + g) * F_DIM + f], a);
        redbuf[q * F_DIM + f] = a;
    }
    __syncthreads();
    if (t < F_DIM)
        t1s[t] = ssp(redbuf[t] + redbuf[F_DIM + t] + n_b1[l * F_DIM + t]);
    __syncthreads();

    // phase B: hs += t1s @ W2 + b2
    {
        int q = t >> 7, f = t & 127;
        const float* W2 = n_W2 + l * F_DIM * F_DIM;
        float a = 0.0f;
        int g0 = q * 64;
        for (int g = 0; g < 64; ++g) a = fmaf(t1s[g0 + g], W2[(g0 + g) * F_DIM + f], a);
        redbuf[q * F_DIM + f] = a;
    }
    __syncthreads();
    if (t < F_DIM) {
        float hv = hs[t] + redbuf[t] + redbuf[F_DIM + t] + n_b2[l * F_DIM + t];
        hs[t] = hv;
        if (l < NLAYER - 1) h[i * F_DIM + t] = hv;   // read next dispatch only
    }
    __syncthreads();

    if (l < NLAYER - 1) {
        // phase C: next layer's atom-wise linear, packed half2
        {
            int q = t >> 7, f = t & 127;
            const float* W = aw_W + (l + 1) * F_DIM * F_DIM;
            float a = 0.0f;
            int g0 = q * 64;
            for (int g = 0; g < 64; ++g) a = fmaf(hs[g0 + g], W[(g0 + g) * F_DIM + f], a);
            redbuf[q * F_DIM + f] = a;
        }
        __syncthreads();
        if (t < F_DIM)
            t1s[t] = redbuf[t] + redbuf[F_DIM + t] + aw_b[(l + 1) * F_DIM + t];
        __syncthreads();
        if (t < F_DIM / 2)
            opk_out[i * 64 + t] = h22u(__halves2half2(__float2half(t1s[2 * t]),
                                                      __float2half(t1s[2 * t + 1])));
    } else {
        // output head: out[i] = ssp(hs @ oW1 + ob1) @ oW2 + ob2
        {
            int q = t >> 5, f = t & 31;      // q in [0,8), 16 g each
            float a = 0.0f;
            int g0 = q * 16;
            for (int g = 0; g < 16; ++g) a = fmaf(hs[g0 + g], oW1[(g0 + g) * 32 + f], a);
            redbuf[q * 32 + f] = a;
        }
        __syncthreads();
        float val = 0.0f;
        if (t < 32) {
            float a = ob1[t];
#pragma unroll
            for (int q = 0; q < 8; ++q) a += redbuf[q * 32 + t];
            val = ssp(a) * oW2[t];
        }
#pragma unroll
        for (int off = 16; off > 0; off >>= 1) val += __shfl_xor(val, off, 64);
        if (t == 0) out[i] = val + ob2[0];
    }
}

// ---------------------------------------------------------------------------
extern "C" void kernel_launch(void* const* d_in, const int* in_sizes, int n_in,
                              void* d_out, int out_size, void* d_ws, size_t ws_size,
                              hipStream_t stream) {
    const int*   x     = (const int*)  d_in[0];
    const float* r     = (const float*)d_in[1];
    const float* emb   = (const float*)d_in[2];
    const float* aw_W  = (const float*)d_in[3];
    const float* aw_b  = (const float*)d_in[4];
    const float* cf_W1 = (const float*)d_in[5];
    const float* cf_b1 = (const float*)d_in[6];
    const float* cf_W2 = (const float*)d_in[7];
    const float* cf_b2 = (const float*)d_in[8];
    const float* n_W1  = (const float*)d_in[9];
    const float* n_b1  = (const float*)d_in[10];
    const float* n_W2  = (const float*)d_in[11];
    const float* n_b2  = (const float*)d_in[12];
    const float* oW1   = (const float*)d_in[13];
    const float* ob1   = (const float*)d_in[14];
    const float* oW2   = (const float*)d_in[15];
    const float* ob2   = (const float*)d_in[16];
    float* out = (float*)d_out;

    char* ws = (char*)d_ws;
    uint2*    dpk    = (uint2*)ws;    ws += (size_t)N_ATOMS * N_ATOMS * 8;        // 2 MB
    float*    h      = (float*)ws;    ws += (size_t)N_ATOMS * F_DIM * 4;          // 256 KB
    unsigned* opkA   = (unsigned*)ws; ws += (size_t)N_ATOMS * (F_DIM / 2) * 4;    // 128 KB
    unsigned* opkB   = (unsigned*)ws; ws += (size_t)N_ATOMS * (F_DIM / 2) * 4;    // 128 KB
    uint2*    ptab   = (uint2*)ws;    ws += (size_t)NLAYER * TAB_ROWS * 64 * 8;   // 2.7 MB
    float*    c_part = (float*)ws;    ws += (size_t)N_ATOMS * JSPLIT * F_DIM * 4; // 2 MB
    unsigned* cnt    = (unsigned*)ws;                                             // 6 KB

    prep_build<<<N_ATOMS + NBBLK2, 256, 0, stream>>>(
        x, r, emb, aw_W, aw_b, cf_W1, cf_b1, cf_W2, cf_b2, dpk, h, opkA, ptab, cnt);
    for (int l = 0; l < NLAYER; ++l) {
        unsigned* oin  = (l & 1) ? opkB : opkA;
        unsigned* oout = (l & 1) ? opkA : opkB;
        conv_node<<<N_ATOMS * JSPLIT, 256, 0, stream>>>(
            dpk, oin, ptab, c_part, cnt + l * N_ATOMS,
            n_W1, n_b1, n_W2, n_b2, h, aw_W, aw_b, oout,
            oW1, ob1, oW2, ob2, out, l);
    }
}

// Round 7
// 163.801 us; speedup vs baseline: 2.1322x; 2.1322x over previous
//
#include <hip/hip_runtime.h>
#include <hip/hip_fp16.h>
#include <math.h>

#define N_ATOMS 512
#define F_DIM   128
#define K_RBF   301
#define NLAYER  3
#define GAMMA_C 10.0f
#define LOG2_C  0.6931471805599453f

// Filter lookup table: w_l(d) sampled at step TAB_H; max d = 10*sqrt(3) = 17.32
#define TAB_H     0.01f
#define TAB_INVH  100.0f
#define TAB_ROWS  1768          // 221 * 8, covers up to 17.67
#define RPB       8             // table rows emitted per task (computes RPB+1)
#define NGROUPS   (TAB_ROWS / RPB)          // 221
#define NTASKS    (NGROUPS * NLAYER)        // 663 (row-group, layer) tasks
#define NBBLK2    ((NTASKS + 1) / 2)        // 332 build blocks, 2 tasks each
#define ROW_BYTES 512           // 64 f-pairs * 8 B (uint2 per pair)

__device__ __forceinline__ float ssp(float x) {
    float ax = fabsf(x);
    return fmaxf(x, 0.0f) + log1pf(expf(-ax)) - LOG2_C;
}
__device__ __forceinline__ __half2 u2h2(unsigned u) {
    union { unsigned u; __half2 h; } c; c.u = u; return c.h;
}
__device__ __forceinline__ unsigned h22u(__half2 h) {
    union { unsigned u; __half2 h; } c; c.h = h; return c.u;
}

// ---------------------------------------------------------------------------
// Fused prep + table build.  grid: (512 + 332) x 256   (round-4 proven form)
__global__ void __launch_bounds__(256)
prep_build(const int* __restrict__ x, const float* __restrict__ r,
           const float* __restrict__ emb,
           const float* __restrict__ aw_W, const float* __restrict__ aw_b,
           const float* __restrict__ cf_W1, const float* __restrict__ cf_b1,
           const float* __restrict__ cf_W2, const float* __restrict__ cf_b2,
           uint2* __restrict__ dpk, float* __restrict__ h,
           unsigned* __restrict__ opk, uint2* __restrict__ ptab) {
    __shared__ float hs[F_DIM];
    __shared__ float os[F_DIM];
    __shared__ float red2[2 * F_DIM];
    __shared__ float e_s[2][RPB + 1][34];
    __shared__ float w1_s[2][F_DIM][12];

    if (blockIdx.x < N_ATOMS) {
        // ---- prep path: distances + embedding + layer-0 atomwise ----
        int i = blockIdx.x;
        int t = threadIdx.x;
        float rx = r[i * 3 + 0], ry = r[i * 3 + 1], rz = r[i * 3 + 2];
        if (t < F_DIM) {
            float hv = emb[x[i] * F_DIM + t];
            h[i * F_DIM + t] = hv;
            hs[t] = hv;
        }
        for (int j = t; j < N_ATOMS; j += 256) {
            float dx = rx - r[j * 3 + 0];
            float dy = ry - r[j * 3 + 1];
            float dz = rz - r[j * 3 + 2];
            float d  = sqrtf(dx * dx + dy * dy + dz * dz);
            float xb = d * TAB_INVH;
            int   b  = ::min((int)xb, TAB_ROWS - 2);
            float fr = xb - (float)b;
            __half fh = __float2half(fr);
            dpk[i * N_ATOMS + j] = make_uint2((unsigned)b * ROW_BYTES,
                                              h22u(__halves2half2(fh, fh)));
        }
        __syncthreads();
        // 2-way g-split atomwise GEMV across all 256 threads
        {
            int q = t >> 7, f = t & 127;
            float a = 0.0f;
            int g0 = q * 64;
            for (int g = 0; g < 64; ++g)
                a = fmaf(hs[g0 + g], aw_W[(g0 + g) * F_DIM + f], a);
            red2[q * F_DIM + f] = a;
        }
        __syncthreads();
        if (t < F_DIM) os[t] = red2[t] + red2[F_DIM + t] + aw_b[t];
        __syncthreads();
        if (t < F_DIM / 2)
            opk[i * 64 + t] = h22u(__halves2half2(__float2half(os[2 * t]),
                                                  __float2half(os[2 * t + 1])));
        return;
    }

    // ---- build path: 2 (row-group, layer) tasks per block ----
    int u = threadIdx.x >> 7;
    int f = threadIdx.x & 127;
    int task = (blockIdx.x - N_ATOMS) * 2 + u;
    bool valid = task < NTASKS;
    task = valid ? task : NTASKS - 1;
    int l    = task / NGROUPS;
    int row0 = (task % NGROUPS) * RPB;

    float dlo = row0 * TAB_H;
    float dhi = (row0 + RPB) * TAB_H;
    // Gaussian window: exp(-10*1.45^2) ~ 7.6e-10 truncation
    int k0 = ::max(0, (int)ceilf((dlo - 1.45f) * 10.0f));
    int k1 = ::min(K_RBF - 1, (int)floorf((dhi + 1.45f) * 10.0f));
    int kw = k1 - k0 + 1;

    for (int idx = f; idx < (RPB + 1) * kw; idx += F_DIM) {
        int rr = idx / kw, kk = idx % kw;
        float dv = (row0 + rr) * TAB_H;
        float tt = dv - 0.1f * (float)(k0 + kk);
        e_s[u][rr][kk] = expf(-GAMMA_C * tt * tt);
    }
    __syncthreads();

    const float* W1 = cf_W1 + l * K_RBF * F_DIM;
    float b1v = cf_b1[l * F_DIM + f];
    float acc[RPB + 1];
#pragma unroll
    for (int rr = 0; rr <= RPB; ++rr) acc[rr] = b1v;
    for (int kk = 0; kk < kw; ++kk) {
        float w1v = W1[(k0 + kk) * F_DIM + f];
#pragma unroll
        for (int rr = 0; rr <= RPB; ++rr) acc[rr] = fmaf(e_s[u][rr][kk], w1v, acc[rr]);
    }
#pragma unroll
    for (int rr = 0; rr <= RPB; ++rr) w1_s[u][f][rr] = ssp(acc[rr]);
    __syncthreads();

    const float* W2 = cf_W2 + l * F_DIM * F_DIM;
    float b2v = cf_b2[l * F_DIM + f];
    float acc2[RPB + 1];
#pragma unroll
    for (int rr = 0; rr <= RPB; ++rr) acc2[rr] = b2v;
    for (int g = 0; g < F_DIM; ++g) {
        float w2v = W2[g * F_DIM + f];
        float4 wa = *(const float4*)&w1_s[u][g][0];
        float4 wb = *(const float4*)&w1_s[u][g][4];
        float  wc = w1_s[u][g][8];
        acc2[0] = fmaf(wa.x, w2v, acc2[0]);
        acc2[1] = fmaf(wa.y, w2v, acc2[1]);
        acc2[2] = fmaf(wa.z, w2v, acc2[2]);
        acc2[3] = fmaf(wa.w, w2v, acc2[3]);
        acc2[4] = fmaf(wb.x, w2v, acc2[4]);
        acc2[5] = fmaf(wb.y, w2v, acc2[5]);
        acc2[6] = fmaf(wb.z, w2v, acc2[6]);
        acc2[7] = fmaf(wb.w, w2v, acc2[7]);
        acc2[8] = fmaf(wc,   w2v, acc2[8]);
    }
    float o9[RPB + 1];
#pragma unroll
    for (int rr = 0; rr <= RPB; ++rr) o9[rr] = ssp(acc2[rr]);

    // pack via same-wave shfl with lane f^1; even lanes write pair p=f>>1
    if (valid) {
        int p = f >> 1;
        bool odd = (f & 1);
#pragma unroll
        for (int rr = 0; rr < RPB; ++rr) {
            float t0 = o9[rr];
            float dt = o9[rr + 1] - o9[rr];
            float ot0 = __shfl_xor(t0, 1, 64);
            float odt = __shfl_xor(dt, 1, 64);
            if (!odd) {
                uint2 v = make_uint2(
                    h22u(__halves2half2(__float2half(t0), __float2half(ot0))),
                    h22u(__halves2half2(__float2half(dt), __float2half(odt))));
                ptab[((size_t)l * TAB_ROWS + row0 + rr) * 64 + p] = v;
            }
        }
    }
}

// ---------------------------------------------------------------------------
// Fused per-layer conv + node (+ next atomwise / output head).
// grid: 512 x 1024 = 2 blocks/CU = 32 waves/CU (hardware max occupancy).
// One block owns atom i entirely: conv over all 512 j (32 jc-groups x 16 j
// per lane, batch-4 gathers), then node MLP with 8-way g-splits.  No c_part
// round trip, no atomics, no cross-block coherence (rounds 1/3/5/6 lesson).
__global__ void __launch_bounds__(1024, 8)
layer_kernel(const uint2* __restrict__ dpk, const unsigned* __restrict__ opk_in,
             const uint2* __restrict__ ptab,
             const float* __restrict__ n_W1, const float* __restrict__ n_b1,
             const float* __restrict__ n_W2, const float* __restrict__ n_b2,
             float* __restrict__ h,
             const float* __restrict__ aw_W, const float* __restrict__ aw_b,
             unsigned* __restrict__ opk_out,
             const float* __restrict__ oW1, const float* __restrict__ ob1,
             const float* __restrict__ oW2, const float* __restrict__ ob2,
             float* __restrict__ out, int l) {
    int i  = blockIdx.x;
    int t  = threadIdx.x;
    int p2 = t & 31;
    int jc = t >> 5;            // 0..31

    __shared__ __align__(16) uint2 ds[N_ATOMS];            // 4 KB
    __shared__ __align__(16) float redbuf[32 * 32 * 4];    // 16 KB, multi-use
    __shared__ __align__(16) float cs[F_DIM];
    __shared__ __align__(16) float t1s[F_DIM];
    __shared__ __align__(16) float hs[F_DIM];

    if (t < N_ATOMS) ds[t] = dpk[i * N_ATOMS + t];
    if (t >= N_ATOMS && t < N_ATOMS + F_DIM) hs[t - N_ATOMS] = h[i * F_DIM + (t - N_ATOMS)];
    __syncthreads();

    // ---- conv: 4 features/lane, 16 j per jc group, batch-4 gathers ----
    const char*  T  = (const char*)(ptab + (size_t)l * TAB_ROWS * 64) + p2 * 16;
    const uint2* ob = (const uint2*)opk_in + p2;           // + j*32 below

    float4 acc = make_float4(0.0f, 0.0f, 0.0f, 0.0f);
    int j0 = jc * 16;
#pragma unroll
    for (int b = 0; b < 4; ++b) {
        uint4 wA = *(const uint4*)&ds[j0 + b * 4];         // j0+b*4, +1
        uint4 wB = *(const uint4*)&ds[j0 + b * 4 + 2];     // +2, +3
        uint2 e0 = make_uint2(wA.x, wA.y), e1 = make_uint2(wA.z, wA.w);
        uint2 e2 = make_uint2(wB.x, wB.y), e3 = make_uint2(wB.z, wB.w);
        uint4 tv0 = *(const uint4*)(T + e0.x);
        uint4 tv1 = *(const uint4*)(T + e1.x);
        uint4 tv2 = *(const uint4*)(T + e2.x);
        uint4 tv3 = *(const uint4*)(T + e3.x);
        uint2 oh0 = ob[(j0 + b * 4 + 0) * 32];
        uint2 oh1 = ob[(j0 + b * 4 + 1) * 32];
        uint2 oh2 = ob[(j0 + b * 4 + 2) * 32];
        uint2 oh3 = ob[(j0 + b * 4 + 3) * 32];
#define CONV_STEP(ee, tv, oh)                                                   \
        {                                                                       \
            __half2 fr2 = u2h2((ee).y);                                         \
            __half2 wa = __hfma2(fr2, u2h2((tv).y), u2h2((tv).x));              \
            __half2 wb = __hfma2(fr2, u2h2((tv).w), u2h2((tv).z));              \
            __half2 oa  = u2h2((oh).x);                                         \
            __half2 obh = u2h2((oh).y);                                         \
            acc.x = fmaf(__half2float(__low2half(wa)),  __half2float(__low2half(oa)),  acc.x); \
            acc.y = fmaf(__half2float(__high2half(wa)), __half2float(__high2half(oa)), acc.y); \
            acc.z = fmaf(__half2float(__low2half(wb)),  __half2float(__low2half(obh)), acc.z); \
            acc.w = fmaf(__half2float(__high2half(wb)), __half2float(__high2half(obh)), acc.w); \
        }
        CONV_STEP(e0, tv0, oh0)
        CONV_STEP(e1, tv1, oh1)
        CONV_STEP(e2, tv2, oh2)
        CONV_STEP(e3, tv3, oh3)
#undef CONV_STEP
    }
    *(float4*)&redbuf[(jc * 32 + p2) * 4] = acc;
    __syncthreads();
    // reduce 32 jc-groups; feature f = 4*pr + c; conflict-free (bank = t%32)
    if (t < F_DIM) {
        int pr = t >> 2, c = t & 3;
        float s = 0.0f;
#pragma unroll
        for (int g = 0; g < 32; ++g) s += redbuf[(g * 32 + pr) * 4 + c];
        cs[t] = s;
    }
    __syncthreads();

    // ---- node MLP, phase A: t1s = ssp(cs @ W1 + b1), 8-way g-split ----
    {
        int q = t >> 7, f = t & 127;             // q in [0,8), 16 g each
        const float* W1 = n_W1 + l * F_DIM * F_DIM;
        float a = 0.0f;
        int g0 = q * 16;
        for (int g = 0; g < 16; ++g) a = fmaf(cs[g0 + g], W1[(g0 + g) * F_DIM + f], a);
        redbuf[q * F_DIM + f] = a;
    }
    __syncthreads();
    if (t < F_DIM) {
        float a = n_b1[l * F_DIM + t];
#pragma unroll
        for (int q = 0; q < 8; ++q) a += redbuf[q * F_DIM + t];
        t1s[t] = ssp(a);
    }
    __syncthreads();

    // ---- phase B: hs += t1s @ W2 + b2 ----
    {
        int q = t >> 7, f = t & 127;
        const float* W2 = n_W2 + l * F_DIM * F_DIM;
        float a = 0.0f;
        int g0 = q * 16;
        for (int g = 0; g < 16; ++g) a = fmaf(t1s[g0 + g], W2[(g0 + g) * F_DIM + f], a);
        redbuf[q * F_DIM + f] = a;
    }
    __syncthreads();
    if (t < F_DIM) {
        float a = n_b2[l * F_DIM + t];
#pragma unroll
        for (int q = 0; q < 8; ++q) a += redbuf[q * F_DIM + t];
        float hv = hs[t] + a;
        hs[t] = hv;
        if (l < NLAYER - 1) h[i * F_DIM + t] = hv;
    }
    __syncthreads();

    if (l < NLAYER - 1) {
        // ---- phase C: next layer's atom-wise linear, packed half2 ----
        {
            int q = t >> 7, f = t & 127;
            const float* W = aw_W + (l + 1) * F_DIM * F_DIM;
            float a = 0.0f;
            int g0 = q * 16;
            for (int g = 0; g < 16; ++g) a = fmaf(hs[g0 + g], W[(g0 + g) * F_DIM + f], a);
            redbuf[q * F_DIM + f] = a;
        }
        __syncthreads();
        if (t < F_DIM) {
            float a = aw_b[(l + 1) * F_DIM + t];
#pragma unroll
            for (int q = 0; q < 8; ++q) a += redbuf[q * F_DIM + t];
            t1s[t] = a;
        }
        __syncthreads();
        if (t < F_DIM / 2)
            opk_out[i * 64 + t] = h22u(__halves2half2(__float2half(t1s[2 * t]),
                                                      __float2half(t1s[2 * t + 1])));
    } else {
        // ---- output head: out[i] = ssp(hs @ oW1 + ob1) @ oW2 + ob2 ----
        {
            int q = t >> 5, f = t & 31;          // q in [0,32), 4 g each
            float a = 0.0f;
            int g0 = q * 4;
            for (int g = 0; g < 4; ++g) a = fmaf(hs[g0 + g], oW1[(g0 + g) * 32 + f], a);
            redbuf[q * 32 + f] = a;
        }
        __syncthreads();
        float val = 0.0f;
        if (t < 32) {
            float a = ob1[t];
#pragma unroll
            for (int q = 0; q < 32; ++q) a += redbuf[q * 32 + t];
            val = ssp(a) * oW2[t];
        }
#pragma unroll
        for (int off = 16; off > 0; off >>= 1) val += __shfl_xor(val, off, 64);
        if (t == 0) out[i] = val + ob2[0];
    }
}

// ---------------------------------------------------------------------------
extern "C" void kernel_launch(void* const* d_in, const int* in_sizes, int n_in,
                              void* d_out, int out_size, void* d_ws, size_t ws_size,
                              hipStream_t stream) {
    const int*   x     = (const int*)  d_in[0];
    const float* r     = (const float*)d_in[1];
    const float* emb   = (const float*)d_in[2];
    const float* aw_W  = (const float*)d_in[3];
    const float* aw_b  = (const float*)d_in[4];
    const float* cf_W1 = (const float*)d_in[5];
    const float* cf_b1 = (const float*)d_in[6];
    const float* cf_W2 = (const float*)d_in[7];
    const float* cf_b2 = (const float*)d_in[8];
    const float* n_W1  = (const float*)d_in[9];
    const float* n_b1  = (const float*)d_in[10];
    const float* n_W2  = (const float*)d_in[11];
    const float* n_b2  = (const float*)d_in[12];
    const float* oW1   = (const float*)d_in[13];
    const float* ob1   = (const float*)d_in[14];
    const float* oW2   = (const float*)d_in[15];
    const float* ob2   = (const float*)d_in[16];
    float* out = (float*)d_out;

    char* ws = (char*)d_ws;
    uint2*    dpk  = (uint2*)ws;    ws += (size_t)N_ATOMS * N_ATOMS * 8;      // 2 MB
    float*    h    = (float*)ws;    ws += (size_t)N_ATOMS * F_DIM * 4;        // 256 KB
    unsigned* opkA = (unsigned*)ws; ws += (size_t)N_ATOMS * (F_DIM / 2) * 4;  // 128 KB
    unsigned* opkB = (unsigned*)ws; ws += (size_t)N_ATOMS * (F_DIM / 2) * 4;  // 128 KB
    uint2*    ptab = (uint2*)ws;                                              // 2.7 MB

    prep_build<<<N_ATOMS + NBBLK2, 256, 0, stream>>>(
        x, r, emb, aw_W, aw_b, cf_W1, cf_b1, cf_W2, cf_b2, dpk, h, opkA, ptab);
    for (int l = 0; l < NLAYER; ++l) {
        unsigned* oin  = (l & 1) ? opkB : opkA;
        unsigned* oout = (l & 1) ? opkA : opkB;
        layer_kernel<<<N_ATOMS, 1024, 0, stream>>>(
            dpk, oin, ptab, n_W1, n_b1, n_W2, n_b2, h, aw_W, aw_b, oout,
            oW1, ob1, oW2, ob2, out, l);
    }
}

// Round 8
// 158.667 us; speedup vs baseline: 2.2012x; 1.0324x over previous
//
#include <hip/hip_runtime.h>
#include <hip/hip_fp16.h>
#include <math.h>

#define N_ATOMS 512
#define F_DIM   128
#define K_RBF   301
#define NLAYER  3
#define GAMMA_C 10.0f
#define LOG2_C  0.6931471805599453f

// Filter lookup table: w_l(d) sampled at step TAB_H; max d = 10*sqrt(3) = 17.32
#define TAB_H     0.01f
#define TAB_INVH  100.0f
#define TAB_ROWS  1768          // 221 * 8, covers up to 17.67
#define RPB       8             // table rows emitted per task (computes RPB+1)
#define NGROUPS   (TAB_ROWS / RPB)          // 221
#define NTASKS    (NGROUPS * NLAYER)        // 663 (row-group, layer) tasks
#define NBBLK2    ((NTASKS + 1) / 2)        // 332 build blocks, 2 tasks each
#define ROW_BYTES 512           // 64 f-pairs * 8 B (uint2 per pair)

#define JSPLIT  4               // conv j-dimension split
#define JPB     (N_ATOMS / JSPLIT)   // 128 j per conv block

__device__ __forceinline__ float ssp(float x) {
    float ax = fabsf(x);
    return fmaxf(x, 0.0f) + log1pf(expf(-ax)) - LOG2_C;
}
__device__ __forceinline__ __half2 u2h2(unsigned u) {
    union { unsigned u; __half2 h; } c; c.u = u; return c.h;
}
__device__ __forceinline__ unsigned h22u(__half2 h) {
    union { unsigned u; __half2 h; } c; c.h = h; return c.u;
}

// ---------------------------------------------------------------------------
// Fused prep + table build.  grid: (512 + 332) x 256   (round-4 proven form)
__global__ void __launch_bounds__(256)
prep_build(const int* __restrict__ x, const float* __restrict__ r,
           const float* __restrict__ emb,
           const float* __restrict__ aw_W, const float* __restrict__ aw_b,
           const float* __restrict__ cf_W1, const float* __restrict__ cf_b1,
           const float* __restrict__ cf_W2, const float* __restrict__ cf_b2,
           uint2* __restrict__ dpk, float* __restrict__ h,
           unsigned* __restrict__ opk, uint2* __restrict__ ptab) {
    __shared__ float hs[F_DIM];
    __shared__ float os[F_DIM];
    __shared__ float red2[2 * F_DIM];
    __shared__ float e_s[2][RPB + 1][34];
    __shared__ float w1_s[2][F_DIM][12];

    if (blockIdx.x < N_ATOMS) {
        // ---- prep path: distances + embedding + layer-0 atomwise ----
        int i = blockIdx.x;
        int t = threadIdx.x;
        float rx = r[i * 3 + 0], ry = r[i * 3 + 1], rz = r[i * 3 + 2];
        if (t < F_DIM) {
            float hv = emb[x[i] * F_DIM + t];
            h[i * F_DIM + t] = hv;
            hs[t] = hv;
        }
        for (int j = t; j < N_ATOMS; j += 256) {
            float dx = rx - r[j * 3 + 0];
            float dy = ry - r[j * 3 + 1];
            float dz = rz - r[j * 3 + 2];
            float d  = sqrtf(dx * dx + dy * dy + dz * dz);
            float xb = d * TAB_INVH;
            int   b  = ::min((int)xb, TAB_ROWS - 2);
            float fr = xb - (float)b;
            __half fh = __float2half(fr);
            dpk[i * N_ATOMS + j] = make_uint2((unsigned)b * ROW_BYTES,
                                              h22u(__halves2half2(fh, fh)));
        }
        __syncthreads();
        // 2-way g-split atomwise GEMV across all 256 threads
        {
            int q = t >> 7, f = t & 127;
            float a = 0.0f;
            int g0 = q * 64;
            for (int g = 0; g < 64; ++g)
                a = fmaf(hs[g0 + g], aw_W[(g0 + g) * F_DIM + f], a);
            red2[q * F_DIM + f] = a;
        }
        __syncthreads();
        if (t < F_DIM) os[t] = red2[t] + red2[F_DIM + t] + aw_b[t];
        __syncthreads();
        if (t < F_DIM / 2)
            opk[i * 64 + t] = h22u(__halves2half2(__float2half(os[2 * t]),
                                                  __float2half(os[2 * t + 1])));
        return;
    }

    // ---- build path: 2 (row-group, layer) tasks per block ----
    int u = threadIdx.x >> 7;
    int f = threadIdx.x & 127;
    int task = (blockIdx.x - N_ATOMS) * 2 + u;
    bool valid = task < NTASKS;
    task = valid ? task : NTASKS - 1;
    int l    = task / NGROUPS;
    int row0 = (task % NGROUPS) * RPB;

    float dlo = row0 * TAB_H;
    float dhi = (row0 + RPB) * TAB_H;
    // Gaussian window: exp(-10*1.45^2) ~ 7.6e-10 truncation
    int k0 = ::max(0, (int)ceilf((dlo - 1.45f) * 10.0f));
    int k1 = ::min(K_RBF - 1, (int)floorf((dhi + 1.45f) * 10.0f));
    int kw = k1 - k0 + 1;

    for (int idx = f; idx < (RPB + 1) * kw; idx += F_DIM) {
        int rr = idx / kw, kk = idx % kw;
        float dv = (row0 + rr) * TAB_H;
        float tt = dv - 0.1f * (float)(k0 + kk);
        e_s[u][rr][kk] = expf(-GAMMA_C * tt * tt);
    }
    __syncthreads();

    const float* W1 = cf_W1 + l * K_RBF * F_DIM;
    float b1v = cf_b1[l * F_DIM + f];
    float acc[RPB + 1];
#pragma unroll
    for (int rr = 0; rr <= RPB; ++rr) acc[rr] = b1v;
    for (int kk = 0; kk < kw; ++kk) {
        float w1v = W1[(k0 + kk) * F_DIM + f];
#pragma unroll
        for (int rr = 0; rr <= RPB; ++rr) acc[rr] = fmaf(e_s[u][rr][kk], w1v, acc[rr]);
    }
#pragma unroll
    for (int rr = 0; rr <= RPB; ++rr) w1_s[u][f][rr] = ssp(acc[rr]);
    __syncthreads();

    const float* W2 = cf_W2 + l * F_DIM * F_DIM;
    float b2v = cf_b2[l * F_DIM + f];
    float acc2[RPB + 1];
#pragma unroll
    for (int rr = 0; rr <= RPB; ++rr) acc2[rr] = b2v;
    for (int g = 0; g < F_DIM; ++g) {
        float w2v = W2[g * F_DIM + f];
        float4 wa = *(const float4*)&w1_s[u][g][0];
        float4 wb = *(const float4*)&w1_s[u][g][4];
        float  wc = w1_s[u][g][8];
        acc2[0] = fmaf(wa.x, w2v, acc2[0]);
        acc2[1] = fmaf(wa.y, w2v, acc2[1]);
        acc2[2] = fmaf(wa.z, w2v, acc2[2]);
        acc2[3] = fmaf(wa.w, w2v, acc2[3]);
        acc2[4] = fmaf(wb.x, w2v, acc2[4]);
        acc2[5] = fmaf(wb.y, w2v, acc2[5]);
        acc2[6] = fmaf(wb.z, w2v, acc2[6]);
        acc2[7] = fmaf(wb.w, w2v, acc2[7]);
        acc2[8] = fmaf(wc,   w2v, acc2[8]);
    }
    float o9[RPB + 1];
#pragma unroll
    for (int rr = 0; rr <= RPB; ++rr) o9[rr] = ssp(acc2[rr]);

    // pack via same-wave shfl with lane f^1; even lanes write pair p=f>>1
    if (valid) {
        int p = f >> 1;
        bool odd = (f & 1);
#pragma unroll
        for (int rr = 0; rr < RPB; ++rr) {
            float t0 = o9[rr];
            float dt = o9[rr + 1] - o9[rr];
            float ot0 = __shfl_xor(t0, 1, 64);
            float odt = __shfl_xor(dt, 1, 64);
            if (!odd) {
                uint2 v = make_uint2(
                    h22u(__halves2half2(__float2half(t0), __float2half(ot0))),
                    h22u(__halves2half2(__float2half(dt), __float2half(odt))));
                ptab[((size_t)l * TAB_ROWS + row0 + rr) * 64 + p] = v;
            }
        }
    }
}

// ---------------------------------------------------------------------------
// Conv, 8-features-per-lane wide-load layout.  grid: (512*4) x 256.
// __launch_bounds__(256,4): 128-VGPR budget so the 24 dwordx4 gathers per
// lane can stay in flight (R4 lesson: (256,8) compiled to VGPR=32 and
// serialized the batches).  Lane p1 = t&15 owns features 8p1..8p1+7;
// jg = t>>4 in [0,16) covers 8 j each.  Per j: 2x16B table + 1x16B opk.
__global__ void __launch_bounds__(256, 4)
conv_kernel(const uint2* __restrict__ dpk, const unsigned* __restrict__ opk_in,
            const uint2* __restrict__ ptab, float* __restrict__ c_part, int l) {
    int bid = blockIdx.x;
    int i  = bid >> 2;
    int qs = bid & 3;
    int t  = threadIdx.x;
    int p1 = t & 15;
    int jg = t >> 4;            // 0..15

    __shared__ __align__(16) uint2 ds[JPB];             // 1 KB
    __shared__ __align__(16) float redbuf[16 * F_DIM];  // 8 KB

    if (t < JPB) ds[t] = dpk[i * N_ATOMS + qs * JPB + t];
    __syncthreads();

    const char*     Tbase = (const char*)(ptab + (size_t)l * TAB_ROWS * 64) + p1 * 32;
    const unsigned* ov    = opk_in + (size_t)(qs * JPB) * 64 + 4 * p1;

    float acc[8] = {0.f, 0.f, 0.f, 0.f, 0.f, 0.f, 0.f, 0.f};
    int j0 = jg * 8;

#define CONV8(ee, ta, tb, oh)                                                   \
    {                                                                           \
        __half2 fr2 = u2h2((ee).y);                                             \
        __half2 w0 = __hfma2(fr2, u2h2((ta).y), u2h2((ta).x));                  \
        __half2 w1 = __hfma2(fr2, u2h2((ta).w), u2h2((ta).z));                  \
        __half2 w2 = __hfma2(fr2, u2h2((tb).y), u2h2((tb).x));                  \
        __half2 w3 = __hfma2(fr2, u2h2((tb).w), u2h2((tb).z));                  \
        __half2 o0 = u2h2((oh).x), o1 = u2h2((oh).y);                           \
        __half2 o2 = u2h2((oh).z), o3 = u2h2((oh).w);                           \
        acc[0] = fmaf(__half2float(__low2half(w0)),  __half2float(__low2half(o0)),  acc[0]); \
        acc[1] = fmaf(__half2float(__high2half(w0)), __half2float(__high2half(o0)), acc[1]); \
        acc[2] = fmaf(__half2float(__low2half(w1)),  __half2float(__low2half(o1)),  acc[2]); \
        acc[3] = fmaf(__half2float(__high2half(w1)), __half2float(__high2half(o1)), acc[3]); \
        acc[4] = fmaf(__half2float(__low2half(w2)),  __half2float(__low2half(o2)),  acc[4]); \
        acc[5] = fmaf(__half2float(__high2half(w2)), __half2float(__high2half(o2)), acc[5]); \
        acc[6] = fmaf(__half2float(__low2half(w3)),  __half2float(__low2half(o3)),  acc[6]); \
        acc[7] = fmaf(__half2float(__high2half(w3)), __half2float(__high2half(o3)), acc[7]); \
    }

#pragma unroll
    for (int jj = 0; jj < 8; jj += 2) {
        uint4 w = *(const uint4*)&ds[j0 + jj];          // descriptors j, j+1
        uint2 eA = make_uint2(w.x, w.y), eB = make_uint2(w.z, w.w);
        const char* TA = Tbase + eA.x;
        const char* TB = Tbase + eB.x;
        uint4 taA = *(const uint4*)TA;
        uint4 tbA = *(const uint4*)(TA + 16);
        uint4 taB = *(const uint4*)TB;
        uint4 tbB = *(const uint4*)(TB + 16);
        uint4 ohA = *(const uint4*)(ov + (size_t)(j0 + jj) * 64);
        uint4 ohB = *(const uint4*)(ov + (size_t)(j0 + jj + 1) * 64);
        CONV8(eA, taA, tbA, ohA)
        CONV8(eB, taB, tbB, ohB)
    }
#undef CONV8

    *(float4*)&redbuf[jg * F_DIM + 8 * p1]     = make_float4(acc[0], acc[1], acc[2], acc[3]);
    *(float4*)&redbuf[jg * F_DIM + 8 * p1 + 4] = make_float4(acc[4], acc[5], acc[6], acc[7]);
    __syncthreads();
    if (t < F_DIM) {
        float s = 0.0f;
#pragma unroll
        for (int g = 0; g < 16; ++g) s += redbuf[g * F_DIM + t];
        c_part[((size_t)(i * JSPLIT + qs)) * F_DIM + t] = s;
    }
}

// ---------------------------------------------------------------------------
// Node MLP (+ next atomwise / output head).  grid: 512 x 256.  (R2 proven)
__global__ void __launch_bounds__(256)
node_kernel(const float* __restrict__ c_part,
            const float* __restrict__ n_W1, const float* __restrict__ n_b1,
            const float* __restrict__ n_W2, const float* __restrict__ n_b2,
            float* __restrict__ h,
            const float* __restrict__ aw_W, const float* __restrict__ aw_b,
            unsigned* __restrict__ opk_out,
            const float* __restrict__ oW1, const float* __restrict__ ob1,
            const float* __restrict__ oW2, const float* __restrict__ ob2,
            float* __restrict__ out, int l) {
    int i = blockIdx.x;
    int t = threadIdx.x;

    __shared__ __align__(16) float cs[F_DIM];
    __shared__ __align__(16) float t1s[F_DIM];
    __shared__ __align__(16) float hs[F_DIM];
    __shared__ __align__(16) float redbuf[2 * F_DIM];

    if (t < F_DIM) {
        const float* cp = c_part + (size_t)i * JSPLIT * F_DIM + t;
        cs[t] = (cp[0] + cp[F_DIM]) + (cp[2 * F_DIM] + cp[3 * F_DIM]);
        hs[t] = h[i * F_DIM + t];
    }
    __syncthreads();

    // ---- phase A: t1s = ssp(cs @ W1 + b1), 2-way g-split ----
    {
        int q = t >> 7, f = t & 127;         // q in [0,2), 64 g each
        const float* W1 = n_W1 + l * F_DIM * F_DIM;
        float a = 0.0f;
        int g0 = q * 64;
        for (int g = 0; g < 64; ++g) a = fmaf(cs[g0 + g], W1[(g0 + g) * F_DIM + f], a);
        redbuf[q * F_DIM + f] = a;
    }
    __syncthreads();
    if (t < F_DIM)
        t1s[t] = ssp(redbuf[t] + redbuf[F_DIM + t] + n_b1[l * F_DIM + t]);
    __syncthreads();

    // ---- phase B: hs += t1s @ W2 + b2 ----
    {
        int q = t >> 7, f = t & 127;
        const float* W2 = n_W2 + l * F_DIM * F_DIM;
        float a = 0.0f;
        int g0 = q * 64;
        for (int g = 0; g < 64; ++g) a = fmaf(t1s[g0 + g], W2[(g0 + g) * F_DIM + f], a);
        redbuf[q * F_DIM + f] = a;
    }
    __syncthreads();
    if (t < F_DIM) {
        float hv = hs[t] + redbuf[t] + redbuf[F_DIM + t] + n_b2[l * F_DIM + t];
        hs[t] = hv;
        if (l < NLAYER - 1) h[i * F_DIM + t] = hv;
    }
    __syncthreads();

    if (l < NLAYER - 1) {
        // ---- phase C: next layer's atom-wise linear, packed half2 ----
        {
            int q = t >> 7, f = t & 127;
            const float* W = aw_W + (l + 1) * F_DIM * F_DIM;
            float a = 0.0f;
            int g0 = q * 64;
            for (int g = 0; g < 64; ++g) a = fmaf(hs[g0 + g], W[(g0 + g) * F_DIM + f], a);
            redbuf[q * F_DIM + f] = a;
        }
        __syncthreads();
        if (t < F_DIM) {
            t1s[t] = redbuf[t] + redbuf[F_DIM + t] + aw_b[(l + 1) * F_DIM + t];
        }
        __syncthreads();
        if (t < F_DIM / 2)
            opk_out[i * 64 + t] = h22u(__halves2half2(__float2half(t1s[2 * t]),
                                                      __float2half(t1s[2 * t + 1])));
    } else {
        // ---- output head: out[i] = ssp(hs @ oW1 + ob1) @ oW2 + ob2 ----
        {
            int q = t >> 5, f = t & 31;      // q in [0,8), 16 g each
            float a = 0.0f;
            int g0 = q * 16;
            for (int g = 0; g < 16; ++g) a = fmaf(hs[g0 + g], oW1[(g0 + g) * 32 + f], a);
            redbuf[q * 32 + f] = a;
        }
        __syncthreads();
        float val = 0.0f;
        if (t < 32) {
            float a = ob1[t];
#pragma unroll
            for (int q = 0; q < 8; ++q) a += redbuf[q * 32 + t];
            val = ssp(a) * oW2[t];
        }
#pragma unroll
        for (int off = 16; off > 0; off >>= 1) val += __shfl_xor(val, off, 64);
        if (t == 0) out[i] = val + ob2[0];
    }
}

// ---------------------------------------------------------------------------
extern "C" void kernel_launch(void* const* d_in, const int* in_sizes, int n_in,
                              void* d_out, int out_size, void* d_ws, size_t ws_size,
                              hipStream_t stream) {
    const int*   x     = (const int*)  d_in[0];
    const float* r     = (const float*)d_in[1];
    const float* emb   = (const float*)d_in[2];
    const float* aw_W  = (const float*)d_in[3];
    const float* aw_b  = (const float*)d_in[4];
    const float* cf_W1 = (const float*)d_in[5];
    const float* cf_b1 = (const float*)d_in[6];
    const float* cf_W2 = (const float*)d_in[7];
    const float* cf_b2 = (const float*)d_in[8];
    const float* n_W1  = (const float*)d_in[9];
    const float* n_b1  = (const float*)d_in[10];
    const float* n_W2  = (const float*)d_in[11];
    const float* n_b2  = (const float*)d_in[12];
    const float* oW1   = (const float*)d_in[13];
    const float* ob1   = (const float*)d_in[14];
    const float* oW2   = (const float*)d_in[15];
    const float* ob2   = (const float*)d_in[16];
    float* out = (float*)d_out;

    char* ws = (char*)d_ws;
    uint2*    dpk    = (uint2*)ws;    ws += (size_t)N_ATOMS * N_ATOMS * 8;       // 2 MB
    float*    h      = (float*)ws;    ws += (size_t)N_ATOMS * F_DIM * 4;         // 256 KB
    unsigned* opkA   = (unsigned*)ws; ws += (size_t)N_ATOMS * (F_DIM / 2) * 4;   // 128 KB
    unsigned* opkB   = (unsigned*)ws; ws += (size_t)N_ATOMS * (F_DIM / 2) * 4;   // 128 KB
    uint2*    ptab   = (uint2*)ws;    ws += (size_t)NLAYER * TAB_ROWS * 64 * 8;  // 2.7 MB
    float*    c_part = (float*)ws;                                               // 1 MB

    prep_build<<<N_ATOMS + NBBLK2, 256, 0, stream>>>(
        x, r, emb, aw_W, aw_b, cf_W1, cf_b1, cf_W2, cf_b2, dpk, h, opkA, ptab);
    for (int l = 0; l < NLAYER; ++l) {
        unsigned* oin  = (l & 1) ? opkB : opkA;
        unsigned* oout = (l & 1) ? opkA : opkB;
        conv_kernel<<<N_ATOMS * JSPLIT, 256, 0, stream>>>(dpk, oin, ptab, c_part, l);
        node_kernel<<<N_ATOMS, 256, 0, stream>>>(
            c_part, n_W1, n_b1, n_W2, n_b2, h, aw_W, aw_b, oout,
            oW1, ob1, oW2, ob2, out, l);
    }
}